// Round 1
// baseline (8192.310 us; speedup 1.0000x reference)
//
#include <hip/hip_runtime.h>

#define B_SZ   2048
#define T_ENC  168
#define TEMPD  128
#define HID    1024
#define M_DEC  48

typedef _Float16 f16;
typedef _Float16 half8 __attribute__((ext_vector_type(8)));
typedef float    f32x4 __attribute__((ext_vector_type(4)));

__device__ __forceinline__ float sigf(float x)   { return 1.0f / (1.0f + __expf(-x)); }
__device__ __forceinline__ float tanhf_(float x) { return 2.0f / (1.0f + __expf(-2.0f * x)) - 1.0f; }

// ---------------------------------------------------------------------------
// Prep: fp32 -> fp16 weight conversion, bias combine, dec_Wih split, x_temp init
// ---------------------------------------------------------------------------
__global__ void prep_kernel(
    const float* __restrict__ encWih, const float* __restrict__ encWhh,
    const float* __restrict__ encbih, const float* __restrict__ encbhh,
    const float* __restrict__ decWih, const float* __restrict__ decWhh,
    const float* __restrict__ decbih, const float* __restrict__ decbhh,
    const float* __restrict__ fcW,    const float* __restrict__ temp_seq,
    f16* __restrict__ encWx, f16* __restrict__ encWh,
    f16* __restrict__ decWx, f16* __restrict__ decWh, f16* __restrict__ fcWh,
    float* __restrict__ enc_b, float* __restrict__ dec_b, float* __restrict__ wlast,
    f16* __restrict__ x_temp)
{
    int i = blockIdx.x * blockDim.x + threadIdx.x;
    int n = gridDim.x * blockDim.x;
    for (int idx = i; idx < 4 * HID * HID; idx += n) {
        encWh[idx] = (f16)encWhh[idx];
        decWh[idx] = (f16)decWhh[idx];
        if (idx < 4 * HID * TEMPD) encWx[idx] = (f16)encWih[idx];
        if (idx < 4 * HID * (TEMPD + 1)) {
            int j = idx / (TEMPD + 1);
            int k = idx - j * (TEMPD + 1);
            float v = decWih[idx];
            if (k < TEMPD) decWx[j * TEMPD + k] = (f16)v;
            else           wlast[j] = v;
        }
        if (idx < TEMPD * HID) fcWh[idx] = (f16)fcW[idx];
        if (idx < 4 * HID) {
            enc_b[idx] = encbih[idx] + encbhh[idx];
            dec_b[idx] = decbih[idx] + decbhh[idx];
        }
        if (idx < B_SZ * TEMPD) {
            int b = idx >> 7, k = idx & 127;
            x_temp[idx] = (f16)temp_seq[(size_t)b * (T_ENC * TEMPD) + (T_ENC - 1) * TEMPD + k];
        }
    }
}

// ---------------------------------------------------------------------------
// Fused LSTM step: gates = x @ Wx^T + h @ Wh^T + b ; pointwise LSTM update.
// Tile: BM=128 rows x BN=32 h-cols x 4 gates. Grid (16, 32). 256 threads.
// IS_DEC: x is f16 dense [B,128] plus rank-1 speed term; else fp32 strided.
// ---------------------------------------------------------------------------
template <int IS_DEC>
__global__ __launch_bounds__(256, 2)
void lstm_step_kernel(
    const void* __restrict__ xsrc, int xoff,
    const f16* __restrict__ h_in, f16* __restrict__ h_out,
    float* __restrict__ c,
    const f16* __restrict__ Wx,      // [4H, 128]
    const f16* __restrict__ Wh,      // [4H, 1024]
    const float* __restrict__ bias,  // [4H]
    const float* __restrict__ wlast, // [4H]  (dec)
    const float* __restrict__ speeds,// [B, M_DEC] (dec)
    int m_step)
{
    __shared__ half8 ldsA[128 * 8];  // 128 rows x 8 x 16B  (BMxBK f16)
    __shared__ half8 ldsW[128 * 8];  // (4 gates x 32) rows x BK

    const int tid  = threadIdx.x;
    const int bm   = blockIdx.x;   // 0..15
    const int bn   = blockIdx.y;   // 0..31
    const int lane = tid & 63;
    const int wid  = tid >> 6;
    const int wr   = wid >> 1;     // 0..1 : 64-row half
    const int wc   = wid & 1;      // 0..1 : 16-col half

    f32x4 acc[4][4];               // [gate][m_rep]
    #pragma unroll
    for (int g = 0; g < 4; ++g)
        #pragma unroll
        for (int mr = 0; mr < 4; ++mr)
            acc[g][mr] = (f32x4){0.f, 0.f, 0.f, 0.f};

    const int NKC = (TEMPD + HID) / 64;  // 18
    for (int kc = 0; kc < NKC; ++kc) {
        // ---- stage A (x for kc<2, h otherwise) ----
        if (kc < TEMPD / 64) {
            const int k0 = kc * 64;
            if (IS_DEC) {
                const f16* xs = (const f16*)xsrc;
                #pragma unroll
                for (int it = 0; it < 4; ++it) {
                    int chunk = tid + it * 256;
                    int row = chunk >> 3, slot = chunk & 7;
                    uint4 v = *(const uint4*)(xs + (size_t)(bm * 128 + row) * TEMPD + k0 + slot * 8);
                    *(uint4*)&ldsA[row * 8 + (slot ^ (row & 7))] = v;
                }
            } else {
                const float* xs = (const float*)xsrc;
                #pragma unroll
                for (int it = 0; it < 4; ++it) {
                    int chunk = tid + it * 256;
                    int row = chunk >> 3, slot = chunk & 7;
                    const float* p = xs + (size_t)(bm * 128 + row) * (T_ENC * TEMPD) + xoff + k0 + slot * 8;
                    float4 f0 = ((const float4*)p)[0];
                    float4 f1 = ((const float4*)p)[1];
                    union { uint4 u; f16 h[8]; } cv;
                    cv.h[0] = (f16)f0.x; cv.h[1] = (f16)f0.y; cv.h[2] = (f16)f0.z; cv.h[3] = (f16)f0.w;
                    cv.h[4] = (f16)f1.x; cv.h[5] = (f16)f1.y; cv.h[6] = (f16)f1.z; cv.h[7] = (f16)f1.w;
                    *(uint4*)&ldsA[row * 8 + (slot ^ (row & 7))] = cv.u;
                }
            }
        } else {
            const int k0 = kc * 64 - TEMPD;
            #pragma unroll
            for (int it = 0; it < 4; ++it) {
                int chunk = tid + it * 256;
                int row = chunk >> 3, slot = chunk & 7;
                uint4 v = *(const uint4*)(h_in + (size_t)(bm * 128 + row) * HID + k0 + slot * 8);
                *(uint4*)&ldsA[row * 8 + (slot ^ (row & 7))] = v;
            }
        }
        // ---- stage W: rows = gate*32 + nloc ----
        {
            const f16* Wp; int Wstride, k0w;
            if (kc < TEMPD / 64) { Wp = Wx; Wstride = TEMPD; k0w = kc * 64; }
            else                 { Wp = Wh; Wstride = HID;   k0w = kc * 64 - TEMPD; }
            #pragma unroll
            for (int it = 0; it < 4; ++it) {
                int chunk = tid + it * 256;
                int row = chunk >> 3, slot = chunk & 7;     // row 0..127
                int gate = row >> 5, nloc = row & 31;
                uint4 v = *(const uint4*)(Wp + (size_t)(gate * HID + bn * 32 + nloc) * Wstride + k0w + slot * 8);
                *(uint4*)&ldsW[row * 8 + (slot ^ (row & 7))] = v;
            }
        }
        __syncthreads();
        // ---- MFMA: 2 k-substeps of K=32 ----
        #pragma unroll
        for (int s = 0; s < 2; ++s) {
            half8 af[4];
            #pragma unroll
            for (int mr = 0; mr < 4; ++mr) {
                int row = wr * 64 + mr * 16 + (lane & 15);
                int slot = s * 4 + (lane >> 4);
                af[mr] = ldsA[row * 8 + (slot ^ (row & 7))];
            }
            half8 bf[4];
            #pragma unroll
            for (int g = 0; g < 4; ++g) {
                int row = g * 32 + wc * 16 + (lane & 15);
                int slot = s * 4 + (lane >> 4);
                bf[g] = ldsW[row * 8 + (slot ^ (row & 7))];
            }
            #pragma unroll
            for (int g = 0; g < 4; ++g)
                #pragma unroll
                for (int mr = 0; mr < 4; ++mr)
                    acc[g][mr] = __builtin_amdgcn_mfma_f32_16x16x32_f16(af[mr], bf[g], acc[g][mr], 0, 0, 0);
        }
        __syncthreads();
    }

    // ---- epilogue: LSTM pointwise ----
    const int col_g = bn * 32 + wc * 16 + (lane & 15);
    const float bi = bias[col_g];
    const float bf_ = bias[HID + col_g];
    const float bg = bias[2 * HID + col_g];
    const float bo = bias[3 * HID + col_g];
    float wli = 0.f, wlf = 0.f, wlg = 0.f, wlo = 0.f;
    if (IS_DEC) {
        wli = wlast[col_g];
        wlf = wlast[HID + col_g];
        wlg = wlast[2 * HID + col_g];
        wlo = wlast[3 * HID + col_g];
    }
    #pragma unroll
    for (int mr = 0; mr < 4; ++mr) {
        #pragma unroll
        for (int q = 0; q < 4; ++q) {
            int row_g = bm * 128 + wr * 64 + mr * 16 + (lane >> 4) * 4 + q;
            float pi = acc[0][mr][q] + bi;
            float pf = acc[1][mr][q] + bf_;
            float pg = acc[2][mr][q] + bg;
            float po = acc[3][mr][q] + bo;
            if (IS_DEC) {
                float sp = speeds[(size_t)row_g * M_DEC + m_step];
                pi += sp * wli; pf += sp * wlf; pg += sp * wlg; po += sp * wlo;
            }
            float ii = sigf(pi), ff = sigf(pf), gg = tanhf_(pg), oo = sigf(po);
            size_t idx = (size_t)row_g * HID + col_g;
            float cn = ff * c[idx] + ii * gg;
            c[idx] = cn;
            h_out[idx] = (f16)(oo * tanhf_(cn));
        }
    }
}

// ---------------------------------------------------------------------------
// fc: pred = h @ fcW^T + fcb ; writes fp32 slice of d_out and fp16 x_temp.
// Tile BM=32 x BN=128, grid 64 blocks, 256 threads.
// ---------------------------------------------------------------------------
__global__ __launch_bounds__(256, 2)
void fc_kernel(const f16* __restrict__ h, const f16* __restrict__ fcW,
               const float* __restrict__ fcb,
               float* __restrict__ out, f16* __restrict__ x_next, int m_step)
{
    __shared__ half8 ldsA[32 * 8];
    __shared__ half8 ldsW[128 * 8];
    const int tid  = threadIdx.x;
    const int bm   = blockIdx.x;     // 0..63
    const int lane = tid & 63;
    const int wid  = tid >> 6;
    const int wr   = wid >> 1;       // 16-row half
    const int wc   = wid & 1;        // 64-col half

    f32x4 acc[4];
    #pragma unroll
    for (int nr = 0; nr < 4; ++nr) acc[nr] = (f32x4){0.f, 0.f, 0.f, 0.f};

    for (int kc = 0; kc < HID / 64; ++kc) {
        int k0 = kc * 64;
        {
            int row = tid >> 3, slot = tid & 7;   // 32 rows x 8 slots = 256 chunks
            uint4 v = *(const uint4*)(h + (size_t)(bm * 32 + row) * HID + k0 + slot * 8);
            *(uint4*)&ldsA[row * 8 + (slot ^ (row & 7))] = v;
        }
        #pragma unroll
        for (int it = 0; it < 4; ++it) {          // 128 rows x 8 slots
            int chunk = tid + it * 256;
            int row = chunk >> 3, slot = chunk & 7;
            uint4 v = *(const uint4*)(fcW + (size_t)row * HID + k0 + slot * 8);
            *(uint4*)&ldsW[row * 8 + (slot ^ (row & 7))] = v;
        }
        __syncthreads();
        #pragma unroll
        for (int s = 0; s < 2; ++s) {
            int arow = wr * 16 + (lane & 15);
            int slot = s * 4 + (lane >> 4);
            half8 a = ldsA[arow * 8 + (slot ^ (arow & 7))];
            #pragma unroll
            for (int nr = 0; nr < 4; ++nr) {
                int brow = wc * 64 + nr * 16 + (lane & 15);
                half8 b = ldsW[brow * 8 + (slot ^ (brow & 7))];
                acc[nr] = __builtin_amdgcn_mfma_f32_16x16x32_f16(a, b, acc[nr], 0, 0, 0);
            }
        }
        __syncthreads();
    }
    #pragma unroll
    for (int nr = 0; nr < 4; ++nr)
        #pragma unroll
        for (int q = 0; q < 4; ++q) {
            int row_g = bm * 32 + wr * 16 + (lane >> 4) * 4 + q;
            int col   = wc * 64 + nr * 16 + (lane & 15);
            float v = acc[nr][q] + fcb[col];
            out[(size_t)row_g * (M_DEC * TEMPD) + (size_t)m_step * TEMPD + col] = v;
            x_next[(size_t)row_g * TEMPD + col] = (f16)v;
        }
}

// ---------------------------------------------------------------------------
extern "C" void kernel_launch(void* const* d_in, const int* in_sizes, int n_in,
                              void* d_out, int out_size, void* d_ws, size_t ws_size,
                              hipStream_t stream)
{
    (void)in_sizes; (void)n_in; (void)out_size; (void)ws_size;
    const float* temp_seq   = (const float*)d_in[0];
    const float* avg_speeds = (const float*)d_in[1];
    const float* enc_Wih    = (const float*)d_in[2];
    const float* enc_Whh    = (const float*)d_in[3];
    const float* enc_bih    = (const float*)d_in[4];
    const float* enc_bhh    = (const float*)d_in[5];
    const float* dec_Wih    = (const float*)d_in[6];
    const float* dec_Whh    = (const float*)d_in[7];
    const float* dec_bih    = (const float*)d_in[8];
    const float* dec_bhh    = (const float*)d_in[9];
    const float* fc_W       = (const float*)d_in[10];
    const float* fc_b       = (const float*)d_in[11];
    float* out = (float*)d_out;

    char* ws = (char*)d_ws;
    size_t off = 0;
    auto alloc = [&](size_t bytes) -> void* {
        void* p = ws + off;
        off += (bytes + 255) & ~(size_t)255;
        return p;
    };
    f16*   encWx  = (f16*)alloc((size_t)4 * HID * TEMPD * 2);
    f16*   encWh  = (f16*)alloc((size_t)4 * HID * HID * 2);
    f16*   decWx  = (f16*)alloc((size_t)4 * HID * TEMPD * 2);
    f16*   decWh  = (f16*)alloc((size_t)4 * HID * HID * 2);
    f16*   fcWh   = (f16*)alloc((size_t)TEMPD * HID * 2);
    float* enc_b  = (float*)alloc((size_t)4 * HID * 4);
    float* dec_b  = (float*)alloc((size_t)4 * HID * 4);
    float* wlast  = (float*)alloc((size_t)4 * HID * 4);
    f16*   hA     = (f16*)alloc((size_t)B_SZ * HID * 2);
    f16*   hB     = (f16*)alloc((size_t)B_SZ * HID * 2);
    float* cbuf   = (float*)alloc((size_t)B_SZ * HID * 4);
    f16*   x_temp = (f16*)alloc((size_t)B_SZ * TEMPD * 2);

    hipMemsetAsync(hA,   0, (size_t)B_SZ * HID * 2, stream);
    hipMemsetAsync(cbuf, 0, (size_t)B_SZ * HID * 4, stream);

    prep_kernel<<<16384, 256, 0, stream>>>(
        enc_Wih, enc_Whh, enc_bih, enc_bhh,
        dec_Wih, dec_Whh, dec_bih, dec_bhh,
        fc_W, temp_seq,
        encWx, encWh, decWx, decWh, fcWh,
        enc_b, dec_b, wlast, x_temp);

    f16* hbuf[2] = {hA, hB};
    dim3 grid(16, 32), blk(256);
    for (int t = 0; t < T_ENC; ++t) {
        lstm_step_kernel<0><<<grid, blk, 0, stream>>>(
            (const void*)temp_seq, t * TEMPD,
            hbuf[t & 1], hbuf[(t + 1) & 1], cbuf,
            encWx, encWh, enc_b, nullptr, nullptr, 0);
    }
    for (int m = 0; m < M_DEC; ++m) {
        lstm_step_kernel<1><<<grid, blk, 0, stream>>>(
            (const void*)x_temp, 0,
            hbuf[m & 1], hbuf[(m + 1) & 1], cbuf,
            decWx, decWh, dec_b, wlast, avg_speeds, m);
        fc_kernel<<<64, 256, 0, stream>>>(
            hbuf[(m + 1) & 1], fcWh, fc_b, out, x_temp, m);
    }
}

// Round 2
// 6673.757 us; speedup vs baseline: 1.2275x; 1.2275x over previous
//
#include <hip/hip_runtime.h>
#include <stdint.h>

#define B_SZ   2048
#define T_ENC  168
#define TEMPD  128
#define HID    1024
#define M_DEC  48

typedef _Float16 f16;
typedef _Float16 half8 __attribute__((ext_vector_type(8)));
typedef float    f32x4 __attribute__((ext_vector_type(4)));

__device__ __forceinline__ float sigf(float x)   { return 1.0f / (1.0f + __expf(-x)); }
__device__ __forceinline__ float tanhf_(float x) { return 2.0f / (1.0f + __expf(-2.0f * x)) - 1.0f; }

// Direct global->LDS, 16B per lane. lds ptr must be wave-uniform base.
__device__ __forceinline__ void gld16(const void* g, void* l) {
    __builtin_amdgcn_global_load_lds(
        (const __attribute__((address_space(1))) void*)g,
        (__attribute__((address_space(3))) void*)l, 16, 0, 0);
}

// ---------------------------------------------------------------------------
// prep_misc: merged f16 weights [4H][128+1024], fcW f16, biases, wlast, x_temp
// ---------------------------------------------------------------------------
__global__ void prep_misc(
    const float* __restrict__ encWih, const float* __restrict__ encWhh,
    const float* __restrict__ encbih, const float* __restrict__ encbhh,
    const float* __restrict__ decWih, const float* __restrict__ decWhh,
    const float* __restrict__ decbih, const float* __restrict__ decbhh,
    const float* __restrict__ fcW,    const float* __restrict__ temp_seq,
    f16* __restrict__ Wenc, f16* __restrict__ Wdec0, f16* __restrict__ fcWh,
    float* __restrict__ enc_b, float* __restrict__ dec_b,
    float* __restrict__ wlast, f16* __restrict__ x_temp)
{
    const int NW = 4 * HID * (TEMPD + HID);
    for (int idx = blockIdx.x * blockDim.x + threadIdx.x; idx < NW;
         idx += gridDim.x * blockDim.x) {
        int j = idx / (TEMPD + HID);
        int k = idx - j * (TEMPD + HID);
        Wenc[idx]  = (f16)(k < TEMPD ? encWih[j * TEMPD + k]
                                     : encWhh[(size_t)j * HID + (k - TEMPD)]);
        Wdec0[idx] = (f16)(k < TEMPD ? decWih[j * (TEMPD + 1) + k]
                                     : decWhh[(size_t)j * HID + (k - TEMPD)]);
        if (idx < TEMPD * HID) fcWh[idx] = (f16)fcW[idx];
        if (idx < 4 * HID) {
            enc_b[idx] = encbih[idx] + encbhh[idx];
            dec_b[idx] = decbih[idx] + decbhh[idx];
            wlast[idx] = decWih[idx * (TEMPD + 1) + TEMPD];
        }
        if (idx < B_SZ * TEMPD) {
            int b = idx >> 7, kk = idx & 127;
            x_temp[idx] = (f16)temp_seq[(size_t)b * (T_ENC * TEMPD) + (T_ENC - 1) * TEMPD + kk];
        }
    }
}

// ---------------------------------------------------------------------------
// prep_fold: WdecF = decWhh + decWih_x @ fcW  (fold x_temp=fc(h) into weights)
//            biasF = decb + decWih_x @ fcb
// ---------------------------------------------------------------------------
__global__ void prep_fold(
    const float* __restrict__ decWih, const float* __restrict__ decWhh,
    const float* __restrict__ decbih, const float* __restrict__ decbhh,
    const float* __restrict__ fcW,    const float* __restrict__ fcb,
    f16* __restrict__ WdecF, float* __restrict__ biasF)
{
    __shared__ float wih[TEMPD];
    const int j = blockIdx.x;
    const int k = blockIdx.y * 256 + threadIdx.x;
    if (threadIdx.x < TEMPD) wih[threadIdx.x] = decWih[j * (TEMPD + 1) + threadIdx.x];
    __syncthreads();
    float acc = decWhh[(size_t)j * HID + k];
    #pragma unroll 8
    for (int p = 0; p < TEMPD; ++p) acc += wih[p] * fcW[p * HID + k];
    WdecF[(size_t)j * HID + k] = (f16)acc;
    if (blockIdx.y == 0 && threadIdx.x == 0) {
        float b = decbih[j] + decbhh[j];
        for (int p = 0; p < TEMPD; ++p) b += wih[p] * fcb[p];
        biasF[j] = b;
    }
}

// ---------------------------------------------------------------------------
// Fused LSTM step, 2-phase double-buffered, global_load_lds staging.
// MODE 0: enc (x fp32 from temp_seq, K=1152)
// MODE 1: dec step 0 (x f16 from x_temp, K=1152)
// MODE 2: dec folded (h only, K=1024)
// Tile 128 rows x (4 gates x 32 cols). Grid 512 (XCD-swizzled). 256 threads.
// ---------------------------------------------------------------------------
template <int MODE>
__global__ __launch_bounds__(256, 2)
void lstm_step(
    const void* __restrict__ xsrc, int xoff,
    const f16* __restrict__ h_in, f16* __restrict__ h_out, float* __restrict__ c,
    const f16* __restrict__ W,                 // merged [4096][WS]
    const float* __restrict__ bias,
    const float* __restrict__ wlast, const float* __restrict__ speeds, int m_step)
{
    constexpr int NKC = (MODE == 2) ? 16 : 18;
    constexpr int WS  = (MODE == 2) ? HID : (HID + TEMPD);

    __shared__ half8 ldsA[2][1024];   // 128 rows x 8 chunks, XOR-swizzled image
    __shared__ half8 ldsW[2][1024];

    const int tid  = threadIdx.x;
    const int id   = blockIdx.x;
    const int swzb = (id & 7) * 64 + (id >> 3);   // bijective XCD swizzle (512 % 8 == 0)
    const int bm   = swzb & 15;
    const int bn   = swzb >> 4;
    const int lane = tid & 63;
    const int wid  = tid >> 6;
    const int wr   = wid >> 1;
    const int wc   = wid & 1;

    f32x4 acc[4][4];
    #pragma unroll
    for (int g = 0; g < 4; ++g)
        #pragma unroll
        for (int mr = 0; mr < 4; ++mr)
            acc[g][mr] = (f32x4){0.f, 0.f, 0.f, 0.f};

    auto stage = [&](int b, int kc) {
        // ---- A tile ----
        if (MODE == 0 && kc < 2) {
            const float* xs = (const float*)xsrc;
            #pragma unroll
            for (int it = 0; it < 4; ++it) {
                int chunk = tid + it * 256;
                int row = chunk >> 3, slot = chunk & 7;
                const float* p = xs + (size_t)(bm * 128 + row) * (T_ENC * TEMPD) + xoff + kc * 64 + slot * 8;
                float4 f0 = ((const float4*)p)[0];
                float4 f1 = ((const float4*)p)[1];
                union { uint4 u; f16 h[8]; } cv;
                cv.h[0] = (f16)f0.x; cv.h[1] = (f16)f0.y; cv.h[2] = (f16)f0.z; cv.h[3] = (f16)f0.w;
                cv.h[4] = (f16)f1.x; cv.h[5] = (f16)f1.y; cv.h[6] = (f16)f1.z; cv.h[7] = (f16)f1.w;
                *(uint4*)&ldsA[b][row * 8 + (slot ^ (row & 7))] = cv.u;
            }
        } else if (MODE == 1 && kc < 2) {
            const f16* xs = (const f16*)xsrc;
            #pragma unroll
            for (int it = 0; it < 4; ++it) {
                int p = wid * 256 + it * 64 + lane;
                int row = p >> 3, s = p & 7;
                gld16(xs + (size_t)(bm * 128 + row) * TEMPD + kc * 64 + ((s ^ (row & 7)) << 3),
                      &ldsA[b][wid * 256 + it * 64]);
            }
        } else {
            const int k0 = kc * 64 - (MODE == 2 ? 0 : TEMPD);
            #pragma unroll
            for (int it = 0; it < 4; ++it) {
                int p = wid * 256 + it * 64 + lane;
                int row = p >> 3, s = p & 7;
                gld16(h_in + (size_t)(bm * 128 + row) * HID + k0 + ((s ^ (row & 7)) << 3),
                      &ldsA[b][wid * 256 + it * 64]);
            }
        }
        // ---- W tile (merged layout: no branch) ----
        {
            const int k0 = kc * 64;
            #pragma unroll
            for (int it = 0; it < 4; ++it) {
                int p = wid * 256 + it * 64 + lane;
                int row = p >> 3, s = p & 7;
                int gate = row >> 5, nloc = row & 31;
                gld16(W + (size_t)(gate * HID + bn * 32 + nloc) * WS + k0 + ((s ^ (row & 7)) << 3),
                      &ldsW[b][wid * 256 + it * 64]);
            }
        }
    };

    stage(0, 0);
    __syncthreads();      // compiler drains vmcnt(0) here

    int cur = 0;
    for (int kc = 0; kc < NKC; ++kc) {
        if (kc + 1 < NKC) stage(cur ^ 1, kc + 1);   // prefetch overlaps compute
        #pragma unroll
        for (int s = 0; s < 2; ++s) {
            half8 af[4];
            #pragma unroll
            for (int mr = 0; mr < 4; ++mr) {
                int row = wr * 64 + mr * 16 + (lane & 15);
                int slotk = s * 4 + (lane >> 4);
                af[mr] = ldsA[cur][row * 8 + (slotk ^ (row & 7))];
            }
            half8 bf[4];
            #pragma unroll
            for (int g = 0; g < 4; ++g) {
                int row = g * 32 + wc * 16 + (lane & 15);
                int slotk = s * 4 + (lane >> 4);
                bf[g] = ldsW[cur][row * 8 + (slotk ^ (row & 7))];
            }
            #pragma unroll
            for (int g = 0; g < 4; ++g)
                #pragma unroll
                for (int mr = 0; mr < 4; ++mr)
                    acc[g][mr] = __builtin_amdgcn_mfma_f32_16x16x32_f16(af[mr], bf[g], acc[g][mr], 0, 0, 0);
        }
        __syncthreads();
        cur ^= 1;
    }

    // ---- epilogue: LSTM pointwise ----
    const int col_g = bn * 32 + wc * 16 + (lane & 15);
    const float bi  = bias[col_g];
    const float bf_ = bias[HID + col_g];
    const float bg  = bias[2 * HID + col_g];
    const float bo  = bias[3 * HID + col_g];
    float wli = 0.f, wlf = 0.f, wlg = 0.f, wlo = 0.f;
    if (MODE >= 1) {
        wli = wlast[col_g];
        wlf = wlast[HID + col_g];
        wlg = wlast[2 * HID + col_g];
        wlo = wlast[3 * HID + col_g];
    }
    #pragma unroll
    for (int mr = 0; mr < 4; ++mr) {
        #pragma unroll
        for (int q = 0; q < 4; ++q) {
            int row_g = bm * 128 + wr * 64 + mr * 16 + (lane >> 4) * 4 + q;
            float pi = acc[0][mr][q] + bi;
            float pf = acc[1][mr][q] + bf_;
            float pg = acc[2][mr][q] + bg;
            float po = acc[3][mr][q] + bo;
            if (MODE >= 1) {
                float sp = speeds[(size_t)row_g * M_DEC + m_step];
                pi += sp * wli; pf += sp * wlf; pg += sp * wlg; po += sp * wlo;
            }
            float ii = sigf(pi), ff = sigf(pf), gg = tanhf_(pg), oo = sigf(po);
            size_t idx = (size_t)row_g * HID + col_g;
            float cn = ff * c[idx] + ii * gg;
            c[idx] = cn;
            h_out[idx] = (f16)(oo * tanhf_(cn));
        }
    }
}

// ---------------------------------------------------------------------------
// Batched fc over 16 stored h slots: preds = h @ fcW^T + fcb -> d_out.
// Rows = 16*2048; tile 32x128; grid 1024. 256 threads.
// ---------------------------------------------------------------------------
__global__ __launch_bounds__(256, 2)
void fc_batch(const f16* __restrict__ hist, const f16* __restrict__ fcWh,
              const float* __restrict__ fcb, float* __restrict__ out, int mbase)
{
    __shared__ half8 ldsA[32 * 8];
    __shared__ half8 ldsW[128 * 8];
    const int tid  = threadIdx.x;
    const int lane = tid & 63;
    const int wid  = tid >> 6;
    const int wr   = wid >> 1;
    const int wc   = wid & 1;
    const int bm   = blockIdx.x;          // 0..1023
    const int slot = bm >> 6;             // 16 slots x 64 blocks
    const int b0   = (bm & 63) * 32;
    const f16* hrow = hist + (size_t)slot * (B_SZ * HID) + (size_t)b0 * HID;
    const int  mm   = mbase + slot;

    f32x4 acc[4];
    #pragma unroll
    for (int nr = 0; nr < 4; ++nr) acc[nr] = (f32x4){0.f, 0.f, 0.f, 0.f};

    for (int kc = 0; kc < HID / 64; ++kc) {
        const int k0 = kc * 64;
        {
            int row = tid >> 3, s = tid & 7;   // 256 chunks, 1/thread
            gld16(hrow + (size_t)row * HID + k0 + ((s ^ (row & 7)) << 3), &ldsA[wid * 64]);
        }
        #pragma unroll
        for (int it = 0; it < 4; ++it) {
            int p = wid * 256 + it * 64 + lane;
            int row = p >> 3, s = p & 7;
            gld16(fcWh + (size_t)row * HID + k0 + ((s ^ (row & 7)) << 3), &ldsW[wid * 256 + it * 64]);
        }
        __syncthreads();
        #pragma unroll
        for (int s2 = 0; s2 < 2; ++s2) {
            int arow = wr * 16 + (lane & 15);
            int slotk = s2 * 4 + (lane >> 4);
            half8 a = ldsA[arow * 8 + (slotk ^ (arow & 7))];
            #pragma unroll
            for (int nr = 0; nr < 4; ++nr) {
                int brow = wc * 64 + nr * 16 + (lane & 15);
                half8 bfr = ldsW[brow * 8 + (slotk ^ (brow & 7))];
                acc[nr] = __builtin_amdgcn_mfma_f32_16x16x32_f16(a, bfr, acc[nr], 0, 0, 0);
            }
        }
        __syncthreads();
    }
    #pragma unroll
    for (int nr = 0; nr < 4; ++nr)
        #pragma unroll
        for (int q = 0; q < 4; ++q) {
            int rloc = wr * 16 + (lane >> 4) * 4 + q;
            int col  = wc * 64 + nr * 16 + (lane & 15);
            out[(size_t)(b0 + rloc) * (M_DEC * TEMPD) + (size_t)mm * TEMPD + col] = acc[nr][q] + fcb[col];
        }
}

// ---------------------------------------------------------------------------
extern "C" void kernel_launch(void* const* d_in, const int* in_sizes, int n_in,
                              void* d_out, int out_size, void* d_ws, size_t ws_size,
                              hipStream_t stream)
{
    (void)in_sizes; (void)n_in; (void)out_size; (void)ws_size;
    const float* temp_seq   = (const float*)d_in[0];
    const float* avg_speeds = (const float*)d_in[1];
    const float* enc_Wih    = (const float*)d_in[2];
    const float* enc_Whh    = (const float*)d_in[3];
    const float* enc_bih    = (const float*)d_in[4];
    const float* enc_bhh    = (const float*)d_in[5];
    const float* dec_Wih    = (const float*)d_in[6];
    const float* dec_Whh    = (const float*)d_in[7];
    const float* dec_bih    = (const float*)d_in[8];
    const float* dec_bhh    = (const float*)d_in[9];
    const float* fc_W       = (const float*)d_in[10];
    const float* fc_b       = (const float*)d_in[11];
    float* out = (float*)d_out;

    char* ws = (char*)d_ws;
    size_t off = 0;
    auto alloc = [&](size_t bytes) -> void* {
        void* p = ws + off;
        off += (bytes + 255) & ~(size_t)255;
        return p;
    };
    const size_t SLOT = (size_t)B_SZ * HID;          // h elems per step
    f16*   Wenc   = (f16*)alloc((size_t)4 * HID * (TEMPD + HID) * 2);
    f16*   Wdec0  = (f16*)alloc((size_t)4 * HID * (TEMPD + HID) * 2);
    f16*   WdecF  = (f16*)alloc((size_t)4 * HID * HID * 2);
    f16*   fcWh   = (f16*)alloc((size_t)TEMPD * HID * 2);
    float* enc_b  = (float*)alloc((size_t)4 * HID * 4);
    float* dec_b  = (float*)alloc((size_t)4 * HID * 4);
    float* biasF  = (float*)alloc((size_t)4 * HID * 4);
    float* wlast  = (float*)alloc((size_t)4 * HID * 4);
    f16*   hA     = (f16*)alloc(SLOT * 2);
    f16*   hB     = (f16*)alloc(SLOT * 2);
    float* cbuf   = (float*)alloc(SLOT * 4);
    f16*   x_temp = (f16*)alloc((size_t)B_SZ * TEMPD * 2);
    f16*   hist   = (f16*)alloc(16 * SLOT * 2);      // 64 MB ring for fc batching

    hipMemsetAsync(hA,   0, SLOT * 2, stream);
    hipMemsetAsync(cbuf, 0, SLOT * 4, stream);

    prep_misc<<<8192, 256, 0, stream>>>(
        enc_Wih, enc_Whh, enc_bih, enc_bhh,
        dec_Wih, dec_Whh, dec_bih, dec_bhh,
        fc_W, temp_seq,
        Wenc, Wdec0, fcWh, enc_b, dec_b, wlast, x_temp);
    prep_fold<<<dim3(4096, 4), 256, 0, stream>>>(
        dec_Wih, dec_Whh, dec_bih, dec_bhh, fc_W, fc_b, WdecF, biasF);

    f16* hbuf[2] = {hA, hB};
    for (int t = 0; t < T_ENC; ++t) {
        lstm_step<0><<<512, 256, 0, stream>>>(
            (const void*)temp_seq, t * TEMPD,
            hbuf[t & 1], hbuf[(t + 1) & 1], cbuf,
            Wenc, enc_b, nullptr, nullptr, 0);
    }
    // T_ENC even -> final enc h is in hA
    for (int m = 0; m < M_DEC; ++m) {
        const f16* hin = (m == 0) ? hA : hist + ((size_t)((m - 1) & 15)) * SLOT;
        f16* hout = hist + ((size_t)(m & 15)) * SLOT;
        if (m == 0) {
            lstm_step<1><<<512, 256, 0, stream>>>(
                (const void*)x_temp, 0, hin, hout, cbuf,
                Wdec0, dec_b, wlast, avg_speeds, 0);
        } else {
            lstm_step<2><<<512, 256, 0, stream>>>(
                nullptr, 0, hin, hout, cbuf,
                WdecF, biasF, wlast, avg_speeds, m);
        }
        if ((m & 15) == 15) {
            fc_batch<<<1024, 256, 0, stream>>>(hist, fcWh, fc_b, out, m - 15);
        }
    }
}